// Round 16
// baseline (69.975 us; speedup 1.0000x reference)
//
#include <hip/hip_runtime.h>

#define B 16
#define N 1024
#define NF 128
#define NL 3
#define AH 64
#define HC 192   // NL*AH
#define FCH 128
#define NC 10
#define L2E 1.44269504088896f

typedef __attribute__((ext_vector_type(8))) short bf16x8;
typedef __attribute__((ext_vector_type(4))) float f32x4;
typedef __attribute__((ext_vector_type(4))) unsigned int u32x4;

static __device__ __forceinline__ unsigned short f2bf(float f) {
  unsigned int x = __builtin_bit_cast(unsigned int, f);
  return (unsigned short)((x + 0x7fffu + ((x >> 16) & 1u)) >> 16);   // RNE
}
static __device__ __forceinline__ float bf2f(unsigned short u) {
  unsigned int x = ((unsigned int)u) << 16;
  return __builtin_bit_cast(float, x);
}

// ---------------------------------------------------------------------------
// k_feat: 64 nodes/block; Ws staged per-layer into LDS with next-layer
// register prefetch; outputs h in FRAGMENT order h_f + f1/f2 f32 pre-scaled
// by log2e. Block 0 zeroes pooled. grid = 256 x 256.
// ---------------------------------------------------------------------------
__global__ __launch_bounds__(256, 2) void k_feat(
    const float* __restrict__ x, const float* __restrict__ Ws,
    const float* __restrict__ a1, const float* __restrict__ a2,
    unsigned short* __restrict__ h_f, float* __restrict__ f1g,
    float* __restrict__ f2g, float* __restrict__ pooled)
{
  __shared__ float xs[64][132];                  // 33.8KB; hlds overlays later
  __shared__ unsigned short wl[2][64][136];      // 34.8KB hi/lo for one layer
  unsigned short (*hlds)[72] = (unsigned short(*)[72])&xs[0][0];  // 27.6KB
  const int t = threadIdx.x;
  const int n0g = blockIdx.x * 64;
  const int gb = n0g >> 10, nl0 = n0g & 1023;
  const int wv = t >> 6, lane = t & 63;
  const int lr = lane & 15, lg = lane >> 4;
  const int lrow = wv * 16 + lr;
  const int wcol = t & 63, woct = t >> 6;

  if (blockIdx.x == 0) {                         // zero pooled (12 KB)
    #pragma unroll
    for (int i = 0; i < 12; ++i) pooled[i * 256 + t] = 0.f;
  }

#define LOADW(R, L) {                                                         \
    _Pragma("unroll")                                                         \
    for (int p = 0; p < 4; ++p) {                                             \
      const int oct = p * 4 + woct;                                           \
      _Pragma("unroll")                                                       \
      for (int i = 0; i < 8; ++i)                                             \
        R[p][i] = Ws[((size_t)(L) * NF + oct * 8 + i) * AH + wcol];           \
    } }
#define WRITEW(R) {                                                           \
    _Pragma("unroll")                                                         \
    for (int p = 0; p < 4; ++p) {                                             \
      const int oct = p * 4 + woct;                                           \
      bf16x8 hv, lv;                                                          \
      _Pragma("unroll")                                                       \
      for (int i = 0; i < 8; ++i) {                                           \
        const unsigned short hi = f2bf(R[p][i]);                              \
        hv[i] = (short)hi;                                                    \
        lv[i] = (short)f2bf(R[p][i] - bf2f(hi));                              \
      }                                                                       \
      *(bf16x8*)&wl[0][wcol][oct * 8] = hv;                                   \
      *(bf16x8*)&wl[1][wcol][oct * 8] = lv;                                   \
    } }
#define MFMAL(L) {                                                            \
    _Pragma("unroll")                                                         \
    for (int n2 = 0; n2 < 4; ++n2) {                                          \
      const int n = (L) * 4 + n2;                                             \
      _Pragma("unroll")                                                       \
      for (int kf = 0; kf < 4; ++kf) {                                        \
        const bf16x8 whi = *(const bf16x8*)&wl[0][n2 * 16 + lr][kf * 32 + lg * 8]; \
        const bf16x8 wlo = *(const bf16x8*)&wl[1][n2 * 16 + lr][kf * 32 + lg * 8]; \
        acc[n] = __builtin_amdgcn_mfma_f32_16x16x32_bf16(xhi[kf], whi, acc[n], 0, 0, 0); \
        acc[n] = __builtin_amdgcn_mfma_f32_16x16x32_bf16(xhi[kf], wlo, acc[n], 0, 0, 0); \
        acc[n] = __builtin_amdgcn_mfma_f32_16x16x32_bf16(xlo[kf], whi, acc[n], 0, 0, 0); \
      }                                                                       \
    } }

  float wrA[4][8], wrB[4][8];
  LOADW(wrA, 0);

  #pragma unroll
  for (int p = 0; p < 8; ++p) {
    const int q = p * 256 + t;
    const int row = q >> 5, c4 = (q & 31) * 4;
    *(float4*)&xs[row][c4] = *(const float4*)&x[(size_t)(n0g + row) * NF + c4];
  }
  __syncthreads();

  bf16x8 xhi[4], xlo[4];
  #pragma unroll
  for (int kf = 0; kf < 4; ++kf) {
    const float4 q0 = *(const float4*)&xs[lrow][kf * 32 + lg * 8];
    const float4 q1 = *(const float4*)&xs[lrow][kf * 32 + lg * 8 + 4];
    const float xv[8] = {q0.x, q0.y, q0.z, q0.w, q1.x, q1.y, q1.z, q1.w};
    #pragma unroll
    for (int e = 0; e < 8; ++e) {
      const unsigned short hi = f2bf(xv[e]);
      xhi[kf][e] = (short)hi;
      xlo[kf][e] = (short)f2bf(xv[e] - bf2f(hi));
    }
  }

  f32x4 acc[12];
  #pragma unroll
  for (int n = 0; n < 12; ++n) acc[n] = (f32x4){0.f, 0.f, 0.f, 0.f};

  WRITEW(wrA);
  LOADW(wrB, 1);
  __syncthreads();
  MFMAL(0);
  __syncthreads();
  WRITEW(wrB);
  LOADW(wrA, 2);
  __syncthreads();
  MFMAL(1);
  __syncthreads();
  WRITEW(wrA);
  __syncthreads();
  MFMAL(2);

#undef LOADW
#undef WRITEW
#undef MFMAL

  float s1[3][4], s2[3][4];
  #pragma unroll
  for (int l = 0; l < 3; ++l)
    #pragma unroll
    for (int r = 0; r < 4; ++r) { s1[l][r] = 0.f; s2[l][r] = 0.f; }
  #pragma unroll
  for (int n = 0; n < 12; ++n) {
    const int col = n * 16 + lr;
    const float a1v = a1[col] * L2E, a2v = a2[col] * L2E;
    const int l = n >> 2;
    #pragma unroll
    for (int r = 0; r < 4; ++r) {
      s1[l][r] += acc[n][r] * a1v;
      s2[l][r] += acc[n][r] * a2v;
    }
  }
  #pragma unroll
  for (int off = 1; off < 16; off <<= 1)
    #pragma unroll
    for (int l = 0; l < 3; ++l)
      #pragma unroll
      for (int r = 0; r < 4; ++r) {
        s1[l][r] += __shfl_xor(s1[l][r], off);
        s2[l][r] += __shfl_xor(s2[l][r], off);
      }
  if (lr == 0) {
    #pragma unroll
    for (int l = 0; l < 3; ++l)
      #pragma unroll
      for (int r = 0; r < 4; ++r) {
        const int rw = n0g + wv * 16 + lg * 4 + r;
        f1g[(size_t)l * (B * N) + rw] = s1[l][r];
        f2g[(size_t)l * (B * N) + rw] = s2[l][r];
      }
  }

  __syncthreads();                               // xs dead; hlds reuses it
  #pragma unroll
  for (int n = 0; n < 12; ++n) {
    const int col = n * 16 + lr;
    #pragma unroll
    for (int rp = 0; rp < 2; ++rp) {
      const unsigned int pr = (unsigned int)f2bf(acc[n][rp * 2]) |
                              ((unsigned int)f2bf(acc[n][rp * 2 + 1]) << 16);
      *(unsigned int*)&hlds[col][wv * 16 + lg * 4 + rp * 2] = pr;
    }
  }
  __syncthreads();
  #pragma unroll
  for (int p = 0; p < 6; ++p) {
    const int widx = p * 256 + t;
    const int lane_w = widx & 63;
    const int jb2 = (widx >> 6) & 1;
    const int n_w = (widx >> 7) & 3;
    const int l_w = widx >> 9;
    const int col = l_w * 64 + n_w * 16 + (lane_w & 15);
    const int jloc = jb2 * 32 + (lane_w >> 4) * 8;
    const size_t off =
        ((((size_t)(gb * 3 + l_w) * 4 + n_w) * 32 + (nl0 >> 5) + jb2) * 64 + lane_w) * 8;
    *(uint4*)&h_f[off] = *(const uint4*)&hlds[col][jloc];
  }
}

// ---------------------------------------------------------------------------
// k_att: fused adj->mask + 3-layer GAT attention + MFMA PV + ones-column
// denominator + relu + pool. Block reads its OWN 16x1024 adj stripe into a
// 2.1KB LDS chunk-mask (one barrier), then a ZERO-barrier register-double-
// buffered j-loop (masks decoded from LDS, h_f fragment loads from global).
// Kills the k_mask pre-pass entirely. grid = 1024 x 192 (wave = layer).
// ---------------------------------------------------------------------------
__global__ __launch_bounds__(192, 3) void k_att(
    const float* __restrict__ adj, const unsigned short* __restrict__ h_f,
    const float* __restrict__ f1, const float* __restrict__ f2,
    float* __restrict__ pooled)
{
  const int bid = blockIdx.x;
  const int blk = (bid & 7) * 128 + (bid >> 3);  // 8 XCDs x 128: 2 batches/XCD
  const int b = blk >> 6;
  const int i0 = (blk & 63) * 16;
  const int ph = ((bid * 5) & 7) * 128;          // per-block phase stagger
  const int t = threadIdx.x;
  const int l = t >> 6, lane = t & 63;
  const int lr = lane & 15, lg = lane >> 4;
  const int msh = (lg & 1) * 8;

  __shared__ float uvt[NL][2][N];                // 24 KB; wave-private slices
  __shared__ unsigned short sm[16][66];          // 2.1 KB chunk-masks

  // ---- Phase A: adj stripe -> chunk masks (coalesced 64B/lane stream) ----
  const float* ap = adj + ((size_t)(b * N + i0)) * N;
  for (int q = t; q < 1024; q += 192) {
    const int row = q >> 6, ch = q & 63;
    const float* p = ap + (size_t)row * N + ch * 16;
    unsigned int bits = 0;
    #pragma unroll
    for (int qq = 0; qq < 4; ++qq) {
      const uint4 u = *(const uint4*)(p + qq * 4);
      bits |= (u.x ? 1u : 0u) << (qq * 4 + 0);
      bits |= (u.y ? 1u : 0u) << (qq * 4 + 1);
      bits |= (u.z ? 1u : 0u) << (qq * 4 + 2);
      bits |= (u.w ? 1u : 0u) << (qq * 4 + 3);
    }
    sm[row][ch] = (unsigned short)bits;          // bit e = adj[row][ch*16+e]
  }

  // ---- u/v tables + full-N unmasked max (wave l = layer l; wave-private) ----
  const float* f2p = f2 + (size_t)l * (B * N) + b * N;
  float mx = -1e30f;
  #pragma unroll
  for (int ch = 0; ch < 4; ++ch) {
    const int jb = ch * 256 + lane * 4;
    const float4 q = *(const float4*)&f2p[jb];
    mx = fmaxf(mx, fmaxf(fmaxf(q.x, q.y), fmaxf(q.z, q.w)));
    *(float4*)&uvt[l][0][jb] =
        (float4){exp2f(q.x), exp2f(q.y), exp2f(q.z), exp2f(q.w)};
    *(float4*)&uvt[l][1][jb] =
        (float4){exp2f(0.2f * q.x), exp2f(0.2f * q.y), exp2f(0.2f * q.z), exp2f(0.2f * q.w)};
  }
  #pragma unroll
  for (int off = 1; off < 64; off <<= 1) mx = fmaxf(mx, __shfl_xor(mx, off));

  const float f1r = f1[(size_t)l * (B * N) + b * N + i0 + lr];
  const float tts = f1r + mx;
  const float sr = fmaxf(tts, 0.f) + 0.2f * fminf(tts, 0.f);  // valid upper bound
  const float A = exp2f(f1r - sr);
  const float C = exp2f(0.2f * f1r - sr);

  const unsigned short* hfb = h_f + ((size_t)(b * 3 + l)) * 65536;
  const float* ut = &uvt[l][0][0];
  const float* vt = &uvt[l][1][0];
  const bf16x8 ones = {(short)0x3F80, (short)0x3F80, (short)0x3F80, (short)0x3F80,
                       (short)0x3F80, (short)0x3F80, (short)0x3F80, (short)0x3F80};

  f32x4 acc[4];
  #pragma unroll
  for (int n = 0; n < 4; ++n) acc[n] = (f32x4){0.f, 0.f, 0.f, 0.f};
  f32x4 accd = (f32x4){0.f, 0.f, 0.f, 0.f};

  __syncthreads();                               // sm ready (the ONLY barrier)

#define LOADJ(BUF, MW, J) {                                                   \
    const int jj = (J) & (N - 1);                                             \
    const int jt = jj >> 6;                                                   \
    const unsigned int s0 = sm[lr][jt * 4 + (lg >> 1)];                       \
    const unsigned int s1 = sm[lr][jt * 4 + 2 + (lg >> 1)];                   \
    MW = ((s0 >> msh) & 0xffu) | (((s1 >> msh) & 0xffu) << 8);                \
    _Pragma("unroll")                                                         \
    for (int q = 0; q < 8; ++q) {                                             \
      const int ks = q >> 2, n = q & 3;                                       \
      BUF[q] = *(const bf16x8*)&hfb[(((size_t)n * 32 + (jj >> 5) + ks) * 64 + \
                                     lane) * 8];                              \
    } }

#define COMPJ(BUF, MW, J) {                                                   \
    _Pragma("unroll")                                                         \
    for (int ks = 0; ks < 2; ++ks) {                                          \
      const int kb = ((J) & (N - 1)) + ks * 32 + lg * 8;                      \
      const float4 u0 = *(const float4*)&ut[kb];                              \
      const float4 u1 = *(const float4*)&ut[kb + 4];                          \
      const float4 v0 = *(const float4*)&vt[kb];                              \
      const float4 v1 = *(const float4*)&vt[kb + 4];                          \
      const unsigned int mby = ((MW) >> (ks * 8)) & 0xffu;                    \
      const float uu[8] = {u0.x, u0.y, u0.z, u0.w, u1.x, u1.y, u1.z, u1.w};   \
      const float vv[8] = {v0.x, v0.y, v0.z, v0.w, v1.x, v1.y, v1.z, v1.w};   \
      unsigned int pk[4];                                                     \
      _Pragma("unroll")                                                       \
      for (int ep = 0; ep < 4; ++ep) {                                        \
        unsigned int pr[2];                                                   \
        _Pragma("unroll")                                                     \
        for (int h = 0; h < 2; ++h) {                                         \
          const int e = ep * 2 + h;                                           \
          /* leaky(t)=max(t,0.2t); exp2 monotone => P=max(A*u, C*v) */        \
          const float p = fmaxf(A * uu[e], C * vv[e]);                        \
          const unsigned int sel =                                            \
              (unsigned int)(((int)(mby << (31 - e))) >> 31);                 \
          pr[h] = (__builtin_bit_cast(unsigned int, p) + 0x8000u) & sel;      \
        }                                                                     \
        pk[ep] = __builtin_amdgcn_perm(pr[1], pr[0], 0x07060302u);            \
      }                                                                       \
      const u32x4 pkv = {pk[0], pk[1], pk[2], pk[3]};                         \
      const bf16x8 av = __builtin_bit_cast(bf16x8, pkv);                      \
      _Pragma("unroll")                                                       \
      for (int n = 0; n < 4; ++n)                                             \
        acc[n] = __builtin_amdgcn_mfma_f32_16x16x32_bf16(av, BUF[ks * 4 + n], \
                                                         acc[n], 0, 0, 0);    \
      accd = __builtin_amdgcn_mfma_f32_16x16x32_bf16(av, ones, accd, 0, 0, 0);\
    } }

#define SBAR __builtin_amdgcn_sched_barrier(0)

  bf16x8 bA[8], bB[8];
  unsigned int mwA, mwB;
  LOADJ(bA, mwA, ph);
  SBAR;
  for (int j0 = 0; j0 < N; j0 += 128) {
    LOADJ(bB, mwB, ph + j0 + 64);                // next tile in flight
    SBAR;
    COMPJ(bA, mwA, ph + j0);
    SBAR;
    LOADJ(bA, mwA, ph + j0 + 128);               // wraps harmlessly
    SBAR;
    COMPJ(bB, mwB, ph + j0 + 64);
    SBAR;
  }
#undef LOADJ
#undef COMPJ
#undef SBAR

  // epilogue: rows i0+lg*4+r owned by this lane's acc regs; denom from accd
  float dn[4];
  #pragma unroll
  for (int r = 0; r < 4; ++r) dn[r] = 1.f / fmaxf(accd[r], 1e-37f);

  #pragma unroll
  for (int n = 0; n < 4; ++n) {
    float csum = 0.f;
    #pragma unroll
    for (int r = 0; r < 4; ++r) csum += fmaxf(acc[n][r] * dn[r], 0.f);
    csum += __shfl_xor(csum, 16);
    csum += __shfl_xor(csum, 32);
    if (lg == 0) atomicAdd(&pooled[b * HC + l * 64 + n * 16 + lr], csum);
  }
}

// ---------------------------------------------------------------------------
// k_head: mean + FC1(relu) + FC2 + softmax.  grid = B.
// ---------------------------------------------------------------------------
__global__ __launch_bounds__(192) void k_head(
    const float* __restrict__ pooled_sums, const float* __restrict__ W1,
    const float* __restrict__ b1, const float* __restrict__ W2,
    const float* __restrict__ b2, float* __restrict__ out)
{
  const int b = blockIdx.x, t = threadIdx.x;
  __shared__ float pooled[HC];
  __shared__ float z[FCH];
  __shared__ float logits[NC];

  if (t < HC) pooled[t] = pooled_sums[b * HC + t] * (1.f / (float)N);
  __syncthreads();

  if (t < FCH) {
    float a = b1[t];
    #pragma unroll 4
    for (int f = 0; f < HC; ++f) a += pooled[f] * W1[(size_t)f * FCH + t];
    z[t] = a > 0.f ? a : 0.f;
  }
  __syncthreads();

  if (t < NC) {
    float a = b2[t];
    #pragma unroll 4
    for (int f = 0; f < FCH; ++f) a += z[f] * W2[(size_t)f * NC + t];
    logits[t] = a;
  }
  __syncthreads();

  if (t == 0) {
    float mxl = logits[0];
    for (int c = 1; c < NC; ++c) mxl = fmaxf(mxl, logits[c]);
    float e[NC], sum = 0.f;
    for (int c = 0; c < NC; ++c) { e[c] = __expf(logits[c] - mxl); sum += e[c]; }
    const float inv = 1.f / sum;
    for (int c = 0; c < NC; ++c) out[b * NC + c] = e[c] * inv;
  }
}

// ---------------------------------------------------------------------------
extern "C" void kernel_launch(void* const* d_in, const int* in_sizes, int n_in,
                              void* d_out, int out_size, void* d_ws, size_t ws_size,
                              hipStream_t stream)
{
  const float* x   = (const float*)d_in[0];
  const float* adj = (const float*)d_in[1];
  const float* Ws  = (const float*)d_in[2];
  const float* a1  = (const float*)d_in[3];
  const float* a2  = (const float*)d_in[4];
  const float* W1  = (const float*)d_in[5];
  const float* b1  = (const float*)d_in[6];
  const float* W2  = (const float*)d_in[7];
  const float* b2  = (const float*)d_in[8];
  float* out = (float*)d_out;

  // workspace layout (16B aligned chunks)
  unsigned short* h_f   = (unsigned short*)d_ws;                       // 6.29 MB
  float*          f1    = (float*)(h_f + (size_t)B * HC * N);          // 196 KB
  float*          f2    = f1 + (size_t)NL * B * N;                     // 196 KB
  float*          pooled= f2 + (size_t)NL * B * N;                     // 12 KB

  k_feat<<<256, 256, 0, stream>>>(x, Ws, a1, a2, h_f, f1, f2, pooled);
  k_att <<<1024, 192, 0, stream>>>(adj, h_f, f1, f2, pooled);
  k_head<<<B, 192, 0, stream>>>(pooled, W1, b1, W2, b2, out);
}